// Round 4
// baseline (99.913 us; speedup 1.0000x reference)
//
#include <hip/hip_runtime.h>

#define GS   7
#define CCH  490
#define HH   128
#define WW   128
#define HALF 64
#define LDW  140        // padded row stride (floats) for the 64-row half buffer.
                        // 140=4*35: rows start 560B apart (16B-aligned for b128);
                        // phase-B (8 rows x 8 col-segs)/wave lands 2-way bank aliasing max (free).
#define NB   2

typedef float v2f __attribute__((ext_vector_type(2)));

// lgkm-only barrier: LDS producer->consumer visibility without draining vmcnt,
// so the stage-1 register prefetch stays in flight across phase B + pooling.
__device__ __forceinline__ void bar_lds() {
    asm volatile("s_waitcnt lgkmcnt(0)" ::: "memory");
    __builtin_amdgcn_s_barrier();
}

__global__ __launch_bounds__(512, 8) void psroi_fused(
    const float* __restrict__ rois,
    const float* __restrict__ feat,
    const int*   __restrict__ stride_p,
    float*       __restrict__ out)
{
#pragma clang fp contract(off)
    __shared__ float S[HALF * LDW];   // 35,840 B -> 4 blocks/CU (if VGPR <= 64)

    const int bc = blockIdx.x;
    const int b  = bc / CCH;
    const int c  = bc - b * CCH;
    const float* __restrict__ f = feat + (size_t)bc * (HH * WW);
    const int tid = threadIdx.x;

    const int c2 = tid & 63;        // column pair: cols {2*c2, 2*c2+1}
    const int sg = tid >> 6;        // 0..7 == wave id -> uniform branches
    float* sp = &S[(sg * 8) * LDW + 2 * c2];

    // ---- stage-0 loads (rows 0..63): 8x dwordx2, 512B/wave-instr, issued first
    v2f va[8];
    {
        const v2f* fp = (const v2f*)(f + (sg * 8) * WW) + c2;
        #pragma unroll
        for (int i = 0; i < 8; ++i)
            va[i] = fp[i * (WW / 2)];
    }

    // ---- ROI geometry (overlaps load latency). Exact reference op order, fp32.
    const int n = tid;              // 512 threads == 512 rois
    const int bi = (int)rois[n * 5 + 0];
    const float ss = 1.0f / (float)(*stride_p);
    {
    }
    const int d   = c / (GS * GS);
    const int rem = c - d * (GS * GS);
    const int pi  = rem / GS;
    const int pj  = rem - pi * GS;

    const float x1 = rois[n * 5 + 1];
    const float y1 = rois[n * 5 + 2];
    const float x2 = rois[n * 5 + 3];
    const float y2 = rois[n * 5 + 4];

    float rsw = rintf(x1) * ss;
    float rsh = rintf(y1) * ss;
    float rew = (rintf(x2) + 1.0f) * ss;
    float reh = (rintf(y2) + 1.0f) * ss;
    float rwv = rew - rsw;
    float rhv = reh - rsh;
    float rwm = rwv * 1.3f;
    float rhm = rhv * 1.3f;
    float swm = (rsw + rew) * 0.5f - rwm * 0.5f;
    float shm = (rsh + reh) * 0.5f - rhm * 0.5f;
    rwm = fmaxf(rwm, 0.1f);
    rhm = fmaxf(rhm, 0.1f);
    float bin_h = rhm / 7.0f;
    float bin_w = rwm / 7.0f;
    float dh = bin_h * 0.25f;
    float dw = bin_w * 0.25f;

    const float gi = (float)pi;
    const float gj = (float)pj;
    const int hs  = (int)fminf(fmaxf(floorf(shm + gi * bin_h - dh),          0.0f), 128.0f);
    const int he  = (int)fminf(fmaxf(ceilf (shm + (gi + 1.0f) * bin_h + dh), 0.0f), 128.0f);
    const int ws2 = (int)fminf(fmaxf(floorf(swm + gj * bin_w - dw),          0.0f), 128.0f);
    const int we  = (int)fminf(fmaxf(ceilf (swm + (gj + 1.0f) * bin_w + dw), 0.0f), 128.0f);
    const int area = (he - hs) * (we - ws2);
    const bool act = (bi == b);

    // ---- phase B (in-place W-cumsum of the 64-row buffer), used for both stages.
    // thread = (row 0..63, 16-col seg 0..7); wave = 8 rows x 8 segs.
    auto phaseB = [&]() {
#pragma clang fp contract(off)
        const int row = tid >> 3;
        const int s8  = tid & 7;
        float* rp = &S[row * LDW + s8 * 16];

        float u[16];
        #pragma unroll
        for (int i = 0; i < 4; ++i) {   // 4x ds_read_b128
            const float4 q = *(const float4*)&rp[i * 4];
            u[4 * i + 0] = q.x; u[4 * i + 1] = q.y;
            u[4 * i + 2] = q.z; u[4 * i + 3] = q.w;
        }
        #pragma unroll
        for (int i = 1; i < 16; ++i)
            u[i] += u[i - 1];

        const float tot = u[15];        // cross-seg fixup within 8-lane groups
        float off = 0.0f;
        #pragma unroll
        for (int k = 1; k < 8; ++k) {
            const float tk = __shfl_up(tot, k, 64);
            if (s8 > k - 1 && k <= s8) off += 0.0f; // (placeholder removed below)
        }
        // rebuild cleanly: off = sum of tot of segs below, in ascending seg order
        off = 0.0f;
        const float t1 = __shfl_up(tot, 1, 64);
        const float t2 = __shfl_up(tot, 2, 64);
        const float t3 = __shfl_up(tot, 3, 64);
        const float t4 = __shfl_up(tot, 4, 64);
        const float t5 = __shfl_up(tot, 5, 64);
        const float t6 = __shfl_up(tot, 6, 64);
        const float t7 = __shfl_up(tot, 7, 64);
        if (s8 > 6) off += t7;          // seg0 total first (ascending order)
        if (s8 > 5) off += t6;
        if (s8 > 4) off += t5;
        if (s8 > 3) off += t4;
        if (s8 > 2) off += t3;
        if (s8 > 1) off += t2;
        if (s8 > 0) off += t1;

        bar_lds();                      // all reads (incl. row-63 carry) before writes
        #pragma unroll
        for (int i = 0; i < 4; ++i) {   // 4x ds_write_b128 in place
            float4 q;
            q.x = u[4 * i + 0] + off; q.y = u[4 * i + 1] + off;
            q.z = u[4 * i + 2] + off; q.w = u[4 * i + 3] + off;
            *(float4*)&rp[i * 4] = q;
        }
    };

    float Av = 0.0f, Bv = 0.0f, Cv = 0.0f, Dv = 0.0f;
    // corner pickup for rows [lo, lo+64)
    auto pool_reads = [&](int lo) {
        if (act) {
            if (he > 0 && we  > 0 && (he - 1) >= lo && (he - 1) < lo + HALF)
                Av = S[(he - 1 - lo) * LDW + (we - 1)];
            if (hs > 0 && we  > 0 && (hs - 1) >= lo && (hs - 1) < lo + HALF)
                Bv = S[(hs - 1 - lo) * LDW + (we - 1)];
            if (he > 0 && ws2 > 0 && (he - 1) >= lo && (he - 1) < lo + HALF)
                Cv = S[(he - 1 - lo) * LDW + (ws2 - 1)];
            if (hs > 0 && ws2 > 0 && (hs - 1) >= lo && (hs - 1) < lo + HALF)
                Dv = S[(hs - 1 - lo) * LDW + (ws2 - 1)];
        }
    };

    // ================= stage 0: rows 0..63 =================
    #pragma unroll
    for (int i = 1; i < 8; ++i) va[i] += va[i - 1];     // H-scan (2 indep 7-chains)
    *(v2f*)&S[sg * LDW + 2 * c2] = va[7];               // seg totals -> rows 0..7
    bar_lds();
    {
        v2f off = {0.0f, 0.0f};
        #pragma unroll
        for (int s = 0; s < 7; ++s)                     // sg uniform per wave
            if (sg > s) off += *(const v2f*)&S[s * LDW + 2 * c2];
        bar_lds();                                      // reads before overwrite
        #pragma unroll
        for (int i = 0; i < 8; ++i) {
            v2f q = va[i] + off;
            *(v2f*)&sp[i * LDW] = q;
        }
    }

    // ---- prefetch stage 1 (rows 64..127) into vb; stays in flight (lgkm-only bars)
    v2f vb[8];
    {
        const v2f* fp = (const v2f*)(f + (HALF + sg * 8) * WW) + c2;
        #pragma unroll
        for (int i = 0; i < 8; ++i)
            vb[i] = fp[i * (WW / 2)];
    }

    bar_lds();                          // phase-A stage-0 visible
    // column carry for stage 1: H-cumsum at global row 63 (pre-phase-B snapshot)
    const v2f cr = *(const v2f*)&S[63 * LDW + 2 * c2];
    phaseB();                           // internal barrier orders carry read vs writes
    bar_lds();                          // phase-B final visible
    pool_reads(0);
    bar_lds();                          // pool reads done before stage-1 overwrite

    // ================= stage 1: rows 64..127 =================
    #pragma unroll
    for (int i = 1; i < 8; ++i) vb[i] += vb[i - 1];     // waits on prefetch here
    *(v2f*)&S[sg * LDW + 2 * c2] = vb[7];
    bar_lds();
    {
        v2f off = cr;                                   // carry first, then seg totals
        #pragma unroll
        for (int s = 0; s < 7; ++s)
            if (sg > s) off += *(const v2f*)&S[s * LDW + 2 * c2];
        bar_lds();
        #pragma unroll
        for (int i = 0; i < 8; ++i) {
            v2f q = vb[i] + off;
            *(v2f*)&sp[i * LDW] = q;
        }
    }
    bar_lds();
    phaseB();
    bar_lds();
    pool_reads(HALF);

    // ---- combine + store (reference order)
    if (act) {
        const float total = ((Av - Bv) - Cv) + Dv;
        out[(size_t)n * CCH + c] = (area > 0) ? (total / (float)area) : 0.0f;
    }
}

extern "C" void kernel_launch(void* const* d_in, const int* in_sizes, int n_in,
                              void* d_out, int out_size, void* d_ws, size_t ws_size,
                              hipStream_t stream)
{
    const float* rois     = (const float*)d_in[0];
    const float* feat     = (const float*)d_in[1];
    const int*   stride_p = (const int*)d_in[2];
    float*       out      = (float*)d_out;

    dim3 grid(NB * CCH);   // one workgroup per (batch, channel)
    dim3 block(512);
    hipLaunchKernelGGL(psroi_fused, grid, block, 0, stream, rois, feat, stride_p, out);
}

// Round 5
// 97.786 us; speedup vs baseline: 1.0218x; 1.0218x over previous
//
#include <hip/hip_runtime.h>

#define GS   7
#define CCH  490
#define HH   128
#define WW   128
#define LDW  132        // padded LDS row stride (floats): row start = 528 B, 16B-aligned
                        // -> conflict-free b128 row access (phase B) and free b32/b64 col access
#define NB   2
#define NWG  (NB * CCH) // 980
#define NXCD 8

typedef float v2f __attribute__((ext_vector_type(2)));

__global__ __launch_bounds__(512, 4) void psroi_fused(
    const float* __restrict__ rois,
    const float* __restrict__ feat,
    const int*   __restrict__ stride_p,
    float*       __restrict__ out)
{
#pragma clang fp contract(off)
    __shared__ float S[HH * LDW];   // 67,584 B -> 2 blocks/CU

    // ---- XCD-chunked bijective swizzle (m204): hardware round-robins wg->XCD by
    // (wgid % 8). Remap so each XCD owns a CONTIGUOUS bc chunk: the 32 consecutive
    // channels sharing each 128B out-line then write from ONE XCD's L2 -> one line
    // fetch + one full-line writeback instead of 8 partial RMWs.
    // q = 980/8 = 122, r = 980%8 = 4.
    const int w    = blockIdx.x;
    const int xcd  = w & 7;
    const int pos  = w >> 3;
    const int start = (xcd < 4) ? xcd * 123 : 4 * 123 + (xcd - 4) * 122;
    const int bc   = start + pos;

    const int b  = bc / CCH;
    const int c  = bc - b * CCH;
    const float* __restrict__ f = feat + (size_t)bc * (HH * WW);
    const int tid = threadIdx.x;

    // ---- Phase A: cumsum over H. thread = (col-pair, 16-row seg); seg == wave id.
    {
        const int c2 = tid & 63;        // column pair: cols {2*c2, 2*c2+1}
        const int sg = tid >> 6;        // 0..7 == wave id -> uniform branches
        const int r0 = sg * 16;

        v2f v[16];
        const v2f* fp = (const v2f*)(f + r0 * WW) + c2;
        #pragma unroll
        for (int i = 0; i < 16; ++i)    // coalesced: 512B per wave-load
            v[i] = fp[i * (WW / 2)];
        #pragma unroll
        for (int i = 1; i < 16; ++i)    // two independent 15-chains (one per column)
            v[i] += v[i - 1];

        // seg-total exchange through S rows 0..7 (overwritten by final writes later)
        *(v2f*)&S[sg * LDW + 2 * c2] = v[15];
        __syncthreads();
        v2f off = {0.0f, 0.0f};         // sg uniform per wave -> uniform branches
        #pragma unroll
        for (int s = 0; s < 7; ++s)
            if (sg > s) off += *(const v2f*)&S[s * LDW + 2 * c2];
        __syncthreads();                // offset reads done before overwrites

        float* sp = &S[r0 * LDW + 2 * c2];
        #pragma unroll
        for (int i = 0; i < 16; ++i) {  // 16x ds_write_b64, imm offsets
            v2f q = v[i] + off;
            *(v2f*)&sp[i * LDW] = q;
        }
    }
    __syncthreads();

    // ---- Phase B: cumsum over W. thread = (row, 32-col seg); quads share a row.
    {
        const int row = tid >> 2;       // wave = 16 rows x 4 col-segs
        const int ws_ = tid & 3;
        float* rp = &S[row * LDW + ws_ * 32];

        float u[32];
        #pragma unroll
        for (int i = 0; i < 8; ++i) {   // 8x ds_read_b128, imm offsets, conflict-free
            const float4 q = *(const float4*)&rp[i * 4];
            u[4 * i + 0] = q.x; u[4 * i + 1] = q.y;
            u[4 * i + 2] = q.z; u[4 * i + 3] = q.w;
        }
        #pragma unroll
        for (int i = 1; i < 32; ++i)
            u[i] += u[i - 1];

        const float tot = u[31];        // cross-seg fixup: 3 shuffles within quad
        const float t1 = __shfl_up(tot, 1, 64);
        const float t2 = __shfl_up(tot, 2, 64);
        const float t3 = __shfl_up(tot, 3, 64);
        float off = 0.0f;
        if (ws_ > 0) off += t1;
        if (ws_ > 1) off += t2;
        if (ws_ > 2) off += t3;

        #pragma unroll
        for (int i = 0; i < 8; ++i) {   // 8x ds_write_b128 in place
            float4 q;
            q.x = u[4 * i + 0] + off; q.y = u[4 * i + 1] + off;
            q.z = u[4 * i + 2] + off; q.w = u[4 * i + 3] + off;
            *(float4*)&rp[i * 4] = q;
        }
    }
    __syncthreads();

    // ---- Phase 3: pooling — thread n handles roi n for this channel ----
    {
        const int n = tid;              // 512 threads == 512 rois
        const float b_f = rois[n * 5 + 0];
        const int bi = (int)b_f;
        if (bi == b) {
            const float ss = 1.0f / (float)(*stride_p);
            const int d   = c / (GS * GS);
            const int rem = c - d * (GS * GS);
            const int pi  = rem / GS;
            const int pj  = rem - pi * GS;

            const float x1 = rois[n * 5 + 1];
            const float y1 = rois[n * 5 + 2];
            const float x2 = rois[n * 5 + 3];
            const float y2 = rois[n * 5 + 4];

            // exact reference op order, fp32, no contraction
            float rsw = rintf(x1) * ss;
            float rsh = rintf(y1) * ss;
            float rew = (rintf(x2) + 1.0f) * ss;
            float reh = (rintf(y2) + 1.0f) * ss;
            float rwv = rew - rsw;
            float rhv = reh - rsh;
            float rwm = rwv * 1.3f;
            float rhm = rhv * 1.3f;
            float swm = (rsw + rew) * 0.5f - rwm * 0.5f;
            float shm = (rsh + reh) * 0.5f - rhm * 0.5f;
            rwm = fmaxf(rwm, 0.1f);
            rhm = fmaxf(rhm, 0.1f);
            float bin_h = rhm / 7.0f;
            float bin_w = rwm / 7.0f;
            float dh = bin_h * 0.25f;
            float dw = bin_w * 0.25f;

            const float gi = (float)pi;
            const float gj = (float)pj;
            const int hs  = (int)fminf(fmaxf(floorf(shm + gi * bin_h - dh),          0.0f), 128.0f);
            const int he  = (int)fminf(fmaxf(ceilf (shm + (gi + 1.0f) * bin_h + dh), 0.0f), 128.0f);
            const int ws2 = (int)fminf(fmaxf(floorf(swm + gj * bin_w - dw),          0.0f), 128.0f);
            const int we  = (int)fminf(fmaxf(ceilf (swm + (gj + 1.0f) * bin_w + dw), 0.0f), 128.0f);

            const int area = (he - hs) * (we - ws2);
            const float A  = (he > 0 && we  > 0) ? S[(he - 1) * LDW + (we  - 1)] : 0.0f;
            const float Bv = (hs > 0 && we  > 0) ? S[(hs - 1) * LDW + (we  - 1)] : 0.0f;
            const float Cv = (he > 0 && ws2 > 0) ? S[(he - 1) * LDW + (ws2 - 1)] : 0.0f;
            const float Dv = (hs > 0 && ws2 > 0) ? S[(hs - 1) * LDW + (ws2 - 1)] : 0.0f;
            const float total = ((A - Bv) - Cv) + Dv;   // reference order
            out[(size_t)n * CCH + c] = (area > 0) ? (total / (float)area) : 0.0f;
        }
    }
}

extern "C" void kernel_launch(void* const* d_in, const int* in_sizes, int n_in,
                              void* d_out, int out_size, void* d_ws, size_t ws_size,
                              hipStream_t stream)
{
    const float* rois     = (const float*)d_in[0];
    const float* feat     = (const float*)d_in[1];
    const int*   stride_p = (const int*)d_in[2];
    float*       out      = (float*)d_out;

    dim3 grid(NWG);    // one workgroup per (batch, channel), XCD-chunk swizzled in-kernel
    dim3 block(512);
    hipLaunchKernelGGL(psroi_fused, grid, block, 0, stream, rois, feat, stride_p, out);
}